// Round 9
// baseline (183.599 us; speedup 1.0000x reference)
//
#include <hip/hip_runtime.h>
#include <math.h>

#define NN 512
#define MM 31
#define TT 32            // M+1 tokens per node
#define EE 64            // INP = EMB = ATT
#define NREL 200
#define NMAT 201
#define SELF_LOOP 200
#define WSTR 72          // bf16 LDS row stride for the transpose (16B-aligned)

typedef short  short8 __attribute__((ext_vector_type(8)));

__device__ __forceinline__ unsigned short f2bf(float f) {
    union { float f; unsigned int u; } a; a.f = f;
    unsigned int r = a.u + 0x7FFFu + ((a.u >> 16) & 1u);   // RNE
    return (unsigned short)(r >> 16);
}
__device__ __forceinline__ float bf2f(unsigned short u) {
    union { unsigned int u; float f; } a; a.u = ((unsigned int)u) << 16;
    return a.f;
}

// ---------------------------------------------------------------------------
// convert_kernel: 603 blocks, one [64,64] f32 Q/K/V matrix each ->
// transposed bf16 Wt[a][e] (so a GEMV lane streams one contiguous 128B row).
// ---------------------------------------------------------------------------
__global__ __launch_bounds__(256) void convert_kernel(
    const float* __restrict__ Q, const float* __restrict__ K,
    const float* __restrict__ V,
    unsigned short* __restrict__ wt_q, unsigned short* __restrict__ wt_k,
    unsigned short* __restrict__ wt_v)
{
    const int bid = blockIdx.x, tid = threadIdx.x;
    const int r   = bid % NMAT;
    const int mat = bid / NMAT;
    const float* src = (mat == 0 ? Q : mat == 1 ? K : V) + (size_t)r * EE * EE;
    unsigned short* dst = (mat == 0 ? wt_q : mat == 1 ? wt_k : wt_v)
                          + (size_t)r * EE * EE;
    __shared__ unsigned short t_s[EE * WSTR];
    {
        const int e = tid >> 2, aseg = (tid & 3) * 16;
        const float4* s4 = (const float4*)(src + e * EE + aseg);
        float4 f0 = s4[0], f1 = s4[1], f2 = s4[2], f3 = s4[3];
        unsigned short b[16] = {
            f2bf(f0.x), f2bf(f0.y), f2bf(f0.z), f2bf(f0.w),
            f2bf(f1.x), f2bf(f1.y), f2bf(f1.z), f2bf(f1.w),
            f2bf(f2.x), f2bf(f2.y), f2bf(f2.z), f2bf(f2.w),
            f2bf(f3.x), f2bf(f3.y), f2bf(f3.z), f2bf(f3.w) };
        unsigned short* d = &t_s[e * WSTR + aseg];
        *(short8*)d = *(short8*)&b[0];
        *(short8*)(d + 8) = *(short8*)&b[8];
    }
    __syncthreads();
    {
        const int a = tid >> 2, eseg = (tid & 3) * 16;
        unsigned short o[16];
#pragma unroll
        for (int j = 0; j < 16; ++j)
            o[j] = t_s[(eseg + j) * WSTR + a];
        unsigned short* d = dst + a * EE + eseg;
        *(short8*)d = *(short8*)&o[0];
        *(short8*)(d + 8) = *(short8*)&o[8];
    }
}

// ---------------------------------------------------------------------------
// node_kernel: ONE block per node does EVERYTHING in LDS (round-8 redesign:
// deletes memset/atomics/lists/proj-kernel/qkv round-trip).
//   1. stage msg -> x_s f32; curr = h@W_self (4-way split) -> x_s[0]
//   2. GEMV projections with per-token gathered bf16 weights:
//      q/k/v[t][a] = sum_e x[t][e] * Wt[idx[t]][a][e]   (f32 accum)
//      lane a streams Wt row a = one 128B line, 8x short8 loads
//   3. scores -> column softmax -> pooled (att row 0) -> FFN -> out
// Weights (4.7MB bf16 total) stay L2/LLC-hot across the 512 blocks.
// ---------------------------------------------------------------------------
__global__ __launch_bounds__(256) void node_kernel(
    const float* __restrict__ h, const float* __restrict__ W_self,
    const float* __restrict__ msg,
    const int* __restrict__ msg_type, const int* __restrict__ r_label_node,
    const int* __restrict__ r_label_msg,
    const unsigned short* __restrict__ wt_q,
    const unsigned short* __restrict__ wt_k,
    const unsigned short* __restrict__ wt_v,
    const float* __restrict__ ffn_w, const float* __restrict__ ffn_b,
    float* __restrict__ out)
{
    const int n = blockIdx.x, tid = threadIdx.x;

    __shared__ float x_s[TT][EE + 4];
    __shared__ float q_s[TT][EE + 4], k_s[TT][EE + 4], v_s[TT][EE + 4];
    __shared__ float s_s[TT][TT + 1];
    __shared__ float att0[TT], pooled[EE];
    __shared__ float part[4][EE];
    __shared__ int qv_s[TT], kk_s[TT];

    // ---- stage msg rows (f32, coalesced float4) + indices + curr partials --
    if (tid < MM * EE / 8) {                 // 248 threads x 8 floats
        const float4* s4 = (const float4*)(msg + (size_t)n * MM * EE) + tid * 2;
        float4 f0 = s4[0], f1 = s4[1];
        const int idx = tid * 8, m = idx >> 6, e = idx & 63;
        float* d = &x_s[m + 1][e];
        *(float4*)d = f0; *(float4*)(d + 4) = f1;
    }
    if (tid < MM) {
        qv_s[tid + 1] = r_label_msg[n * MM + tid];
        kk_s[tid + 1] = msg_type[n * MM + tid];
    } else if (tid == 40) {
        qv_s[0] = r_label_node[n];
        kk_s[0] = SELF_LOOP;
    }
    {   // curr = h[n] @ W_self, 4-way split over e across all 256 threads
        const int c = tid & 63, p4 = tid >> 6;
        const float* hrow = h + n * EE;
        float acc = 0.f;
#pragma unroll
        for (int e = 0; e < 16; ++e)
            acc = fmaf(hrow[p4 * 16 + e], W_self[(p4 * 16 + e) * EE + c], acc);
        part[p4][c] = acc;
    }
    __syncthreads();
    if (tid < EE)
        x_s[0][tid] = part[0][tid] + part[1][tid] + part[2][tid] + part[3][tid];
    __syncthreads();

    // ---- projections: t = iter*4 + wave, a = lane; 3 mats fused ----------
    {
        const int a = tid & 63;
        const int wv = tid >> 6;
        for (int iter = 0; iter < 8; ++iter) {
            const int t = iter * 4 + wv;
            const int rq = qv_s[t], rk = kk_s[t];
            const unsigned short* Wq = wt_q + ((size_t)rq << 12) + a * EE;
            const unsigned short* Wv = wt_v + ((size_t)rq << 12) + a * EE;
            const unsigned short* Wk = wt_k + ((size_t)rk << 12) + a * EE;
            const float* xr = &x_s[t][0];
            float aq = 0.f, ak = 0.f, av = 0.f;
#pragma unroll
            for (int e8 = 0; e8 < 8; ++e8) {
                short8 wq8 = *(const short8*)(Wq + e8 * 8);
                short8 wk8 = *(const short8*)(Wk + e8 * 8);
                short8 wv8 = *(const short8*)(Wv + e8 * 8);
#pragma unroll
                for (int j = 0; j < 8; ++j) {
                    float xv = xr[e8 * 8 + j];
                    aq = fmaf(xv, bf2f(((unsigned short*)&wq8)[j]), aq);
                    ak = fmaf(xv, bf2f(((unsigned short*)&wk8)[j]), ak);
                    av = fmaf(xv, bf2f(((unsigned short*)&wv8)[j]), av);
                }
            }
            q_s[t][a] = aq; k_s[t][a] = ak; v_s[t][a] = av;
        }
    }
    __syncthreads();

    // ---- scores s[qi][ki] = dot(q[qi],k[ki]) / 8 --------------------------
    {
        const int ki = tid & 31;
        for (int qi = tid >> 5; qi < TT; qi += 8) {
            const float4* qp = (const float4*)&q_s[qi][0];
            const float4* kp = (const float4*)&k_s[ki][0];
            float acc = 0.f;
            for (int e4 = 0; e4 < EE / 4; ++e4) {
                float4 a = qp[e4], b = kp[e4];
                acc += a.x * b.x + a.y * b.y + a.z * b.z + a.w * b.w;
            }
            s_s[qi][ki] = acc * 0.125f;
        }
    }
    __syncthreads();

    // softmax over the QUERY axis per column; only row 0 of att needed
    if (tid < TT) {
        float mx = -INFINITY;
        for (int qi = 0; qi < TT; ++qi) mx = fmaxf(mx, s_s[qi][tid]);
        float sum = 0.f;
        for (int qi = 0; qi < TT; ++qi) sum += __expf(s_s[qi][tid] - mx);
        att0[tid] = __expf(s_s[0][tid] - mx) / sum;
    }
    __syncthreads();

    if (tid < EE) {
        float acc = 0.f;
        for (int ki = 0; ki < TT; ++ki)
            acc = fmaf(att0[ki], v_s[ki][tid], acc);
        pooled[tid] = acc;
    }
    __syncthreads();

    if (tid < EE) {
        float acc = ffn_b[tid];
        for (int a = 0; a < EE; ++a)
            acc = fmaf(pooled[a], ffn_w[a * EE + tid], acc);
        out[n * EE + tid] = acc;
    }
}

extern "C" void kernel_launch(void* const* d_in, const int* in_sizes, int n_in,
                              void* d_out, int out_size, void* d_ws, size_t ws_size,
                              hipStream_t stream) {
    const float* h            = (const float*)d_in[0];
    const float* msg          = (const float*)d_in[1];
    const int*   msg_type     = (const int*)  d_in[2];
    const int*   r_label_node = (const int*)  d_in[3];
    const int*   r_label_msg  = (const int*)  d_in[4];
    const float* W_self       = (const float*)d_in[5];
    const float* Q            = (const float*)d_in[6];
    const float* K            = (const float*)d_in[7];
    const float* V            = (const float*)d_in[8];
    const float* ffn_w        = (const float*)d_in[9];
    const float* ffn_b        = (const float*)d_in[10];
    float*       out          = (float*)d_out;

    // ws layout: just the transposed bf16 weights (3 x 201 x 64 x 64 shorts)
    unsigned short* wt_q = (unsigned short*)d_ws;
    unsigned short* wt_k = wt_q + (size_t)NMAT * EE * EE;
    unsigned short* wt_v = wt_k + (size_t)NMAT * EE * EE;

    convert_kernel<<<3 * NMAT, 256, 0, stream>>>(Q, K, V, wt_q, wt_k, wt_v);
    node_kernel<<<NN, 256, 0, stream>>>(
        h, W_self, msg, msg_type, r_label_node, r_label_msg,
        wt_q, wt_k, wt_v, ffn_w, ffn_b, out);
}